// Round 7
// baseline (281.234 us; speedup 1.0000x reference)
//
#include <hip/hip_runtime.h>
#include <stdint.h>

// TopoSignature via parallel Boruvka MST. Round 7: lane-private block-min in
// scanA. Block b = cols congruent to [4b,4b+4) mod 256 (the cols lane b owns
// under the coalesced mapping), so scanA needs NO cross-lane ops in its loop
// (round-6 version stalled on 8 dependent u64 shuffles per iter). Memory
// patterns identical to round 6; scan2 rescan indices remapped to match.

#define N        4096
#define NROUNDS  12

typedef unsigned long long u64;
typedef uint32_t u32;

#define INFK (~0ull)

struct Ws {
    u64 best[2][N];      // per-component min outgoing edge key: (wbits<<24)|(lo<<12)|hi
    u32 comp[2][N];      // vertex -> component root label
    u32 edges[2][N];     // edge slot per vertex, (lo<<12)|hi; (i<<12)|i = none
    u32 ncomp[2];
    u32 pad[14];
    u64 bm[2][N * 64];   // per-row per-block bound keys: (wbits<<12)|col ; 4 MB
};

__device__ __forceinline__ u64 umin64(u64 a, u64 b) { return a < b ? a : b; }

__device__ __forceinline__ u64 shfl_down_u64(u64 x, int off) {
    u32 lo = (u32)x, hi = (u32)(x >> 32);
    lo = (u32)__shfl_down((int)lo, off, 64);
    hi = (u32)__shfl_down((int)hi, off, 64);
    return ((u64)hi << 32) | lo;
}
__device__ __forceinline__ u64 shfl_xor_u64(u64 x, int off) {
    u32 lo = (u32)x, hi = (u32)(x >> 32);
    lo = (u32)__shfl_xor((int)lo, off, 64);
    hi = (u32)__shfl_xor((int)hi, off, 64);
    return ((u64)hi << 32) | lo;
}

__global__ void init_k(Ws* __restrict__ ws) {
    int i = blockIdx.x * blockDim.x + threadIdx.x;
    if (i < N) {
        ws->best[0][i] = INFK; ws->best[1][i] = INFK;
        ws->comp[0][i] = (u32)i; ws->comp[1][i] = (u32)i;
        u32 diag = ((u32)i << 12) | (u32)i;
        ws->edges[0][i] = diag; ws->edges[1][i] = diag;
        if (i < 2) ws->ncomp[i] = (u32)N;
    }
}

// Round 1: full scan, one wave per row; block minima are lane-private.
// Lane L, iter j covers cols 4L+256j .. 4L+256j+3 (coalesced float4 loads).
__launch_bounds__(256, 8)
__global__ void scanA_k(const float* __restrict__ d1, const float* __restrict__ d2,
                        Ws* __restrict__ ws) {
    const int m = blockIdx.x >> 10;
    const int wave = threadIdx.x >> 6, lane = threadIdx.x & 63;
    const int v = ((blockIdx.x & 1023) << 2) + wave;
    const float4* __restrict__ row4 = (const float4*)((m ? d2 : d1) + (size_t)v * N);
    u64* __restrict__ bmrow = ws->bm[m] + (size_t)v * 64;

    const u32 uv = (u32)v;
    u64 bmin = INFK;                 // private block min (lane's 64 cols)

    #pragma unroll
    for (int j = 0; j < 16; ++j) {
        const int c = lane + 64 * j;
        float4 w = row4[c];
        const u32 c0 = (u32)(4 * c);
        u64 k0 = (((u64)__float_as_uint(w.x)) << 12) | (c0 + 0);
        u64 k1 = (((u64)__float_as_uint(w.y)) << 12) | (c0 + 1);
        u64 k2 = (((u64)__float_as_uint(w.z)) << 12) | (c0 + 2);
        u64 k3 = (((u64)__float_as_uint(w.w)) << 12) | (c0 + 3);
        if (c0 + 0 != uv) bmin = umin64(bmin, k0);
        if (c0 + 1 != uv) bmin = umin64(bmin, k1);
        if (c0 + 2 != uv) bmin = umin64(bmin, k2);
        if (c0 + 3 != uv) bmin = umin64(bmin, k3);
    }

    bmrow[lane] = bmin;              // coalesced 512 B store

    // row min: one 64-lane butterfly at the end
    u64 rowmin = bmin;
    #pragma unroll
    for (int off = 1; off <= 32; off <<= 1)
        rowmin = umin64(rowmin, shfl_xor_u64(rowmin, off));

    if (lane == 0) {
        u32 wb = (u32)(rowmin >> 12);
        u32 u  = (u32)rowmin & 0xFFFu;
        u32 lo = min(uv, u), hi = max(uv, u);
        ws->best[m][v] = ((u64)wb << 24) | ((u64)lo << 12) | (u64)hi;  // comp==v
    }
}

// Rounds 2+: bound-table scan. One wave per row, lane = block.
// Block b = cols {4b+q + 256j : j=0..15, q=0..3}.
__launch_bounds__(256, 8)
__global__ void scan2_k(const float* __restrict__ d1, const float* __restrict__ d2,
                        Ws* __restrict__ ws) {
    const int m = blockIdx.x >> 10;
    if (ws->ncomp[m] <= 1u) return;
    const int wave = threadIdx.x >> 6, lane = threadIdx.x & 63;
    const int v = ((blockIdx.x & 1023) << 2) + wave;

    const float* __restrict__ dm = m ? d2 : d1;
    const u32*   __restrict__ cm = ws->comp[m];
    u64* __restrict__ bmrow = ws->bm[m] + (size_t)v * 64;

    const u32 cv = cm[v];
    u64 key = bmrow[lane];
    bool cross = false;
    if (key != INFK) cross = (cm[(u32)key & 0xFFFu] != cv);

    // best cross candidate among stored block mins (exact entries)
    u64 kb = cross ? key : INFK;
    #pragma unroll
    for (int off = 1; off <= 32; off <<= 1)
        kb = umin64(kb, shfl_xor_u64(kb, off));

    // intra bound undercutting kb -> block may hide a smaller cross entry
    const bool need = (!cross) && (key < kb);
    u64 nm = INFK;
    if (need) {
        const float4* __restrict__ row4 = (const float4*)(dm + (size_t)v * N);
        const uint4*  __restrict__ c4   = (const uint4*)cm;
        #pragma unroll
        for (int j = 0; j < 16; ++j) {
            const int c = lane + 64 * j;
            float4 w = row4[c];
            uint4 cu = c4[c];
            u32 c0 = (u32)(4 * c);
            if (cu.x != cv) nm = umin64(nm, (((u64)__float_as_uint(w.x)) << 12) | (c0 + 0));
            if (cu.y != cv) nm = umin64(nm, (((u64)__float_as_uint(w.y)) << 12) | (c0 + 1));
            if (cu.z != cv) nm = umin64(nm, (((u64)__float_as_uint(w.z)) << 12) | (c0 + 2));
            if (cu.w != cv) nm = umin64(nm, (((u64)__float_as_uint(w.w)) << 12) | (c0 + 3));
        }
        bmrow[lane] = nm;    // tightened bound: block's current min-cross key
    }
    u64 kb2 = need ? nm : INFK;
    #pragma unroll
    for (int off = 1; off <= 32; off <<= 1)
        kb2 = umin64(kb2, shfl_xor_u64(kb2, off));

    u64 fin = umin64(kb, kb2);
    if (lane == 0 && fin != INFK) {
        u32 wb = (u32)(fin >> 12);
        u32 u  = (u32)fin & 0xFFFu;
        u32 lo = min((u32)v, u), hi = max((u32)v, u);
        u64 g  = ((u64)wb << 24) | ((u64)lo << 12) | (u64)hi;
        if (g < ws->best[m][cv])
            atomicMin(&ws->best[m][cv], g);
    }
}

// Fallback full scan (used when ws_size too small for the bound table).
__launch_bounds__(256, 8)
__global__ void scanF_k(const float* __restrict__ d1, const float* __restrict__ d2,
                        Ws* __restrict__ ws, int first) {
    const int m = blockIdx.x >> 10;
    if (ws->ncomp[m] <= 1u) return;
    const int wave = threadIdx.x >> 6, lane = threadIdx.x & 63;
    const int v = ((blockIdx.x & 1023) << 2) + wave;
    const float* __restrict__ dm = m ? d2 : d1;
    const u32*   __restrict__ cm = ws->comp[m];
    const float4* __restrict__ row4 = (const float4*)(dm + (size_t)v * N);
    const uint4*  __restrict__ c4   = (const uint4*)cm;
    const u32 cv = first ? (u32)v : cm[v];
    u64 kmin = INFK;
    #pragma unroll
    for (int j = 0; j < 16; ++j) {
        const int c = lane + 64 * j;
        float4 w = row4[c];
        uint4 cu;
        if (!first) cu = c4[c];
        const u32 c0 = (u32)(4 * c);
        bool x0, x1, x2, x3;
        if (first) {
            const u32 uvv = (u32)v;
            x0 = (c0+0 != uvv); x1 = (c0+1 != uvv); x2 = (c0+2 != uvv); x3 = (c0+3 != uvv);
        } else {
            x0 = (cu.x != cv); x1 = (cu.y != cv); x2 = (cu.z != cv); x3 = (cu.w != cv);
        }
        if (x0) kmin = umin64(kmin, (((u64)__float_as_uint(w.x)) << 12) | (c0 + 0));
        if (x1) kmin = umin64(kmin, (((u64)__float_as_uint(w.y)) << 12) | (c0 + 1));
        if (x2) kmin = umin64(kmin, (((u64)__float_as_uint(w.z)) << 12) | (c0 + 2));
        if (x3) kmin = umin64(kmin, (((u64)__float_as_uint(w.w)) << 12) | (c0 + 3));
    }
    #pragma unroll
    for (int off = 1; off <= 32; off <<= 1)
        kmin = umin64(kmin, shfl_xor_u64(kmin, off));
    if (lane == 0 && kmin != INFK) {
        u32 wb = (u32)(kmin >> 12);
        u32 u  = (u32)kmin & 0xFFFu;
        u32 lo = min((u32)v, u), hi = max((u32)v, u);
        u64 g  = ((u64)wb << 24) | ((u64)lo << 12) | (u64)hi;
        if (first) ws->best[m][v] = g;
        else if (g < ws->best[m][cv]) atomicMin(&ws->best[m][cv], g);
    }
}

// Hook roots, resolve 2-cycles, record edges (slot = dying root id),
// pointer-jump, relabel, reset best. One 1024-thread block per matrix.
__launch_bounds__(1024, 1)
__global__ void hook_k(Ws* __restrict__ ws) {
    const int m = blockIdx.x;
    const int tid = threadIdx.x;
    if (ws->ncomp[m] <= 1u) return;

    u32* __restrict__ gcomp = ws->comp[m];
    u64* __restrict__ best  = ws->best[m];

    __shared__ u32 compL[N];
    __shared__ u32 nxtA[N];
    __shared__ u32 nxtB[N];
    __shared__ u32 red[16];

    {
        uint4* dst = (uint4*)compL;
        const uint4* src = (const uint4*)gcomp;
        if (tid < N / 4) dst[tid] = src[tid];
    }
    __syncthreads();

    bool isroot[4];
    u64  bkey[4];

    #pragma unroll
    for (int k = 0; k < 4; ++k) {
        int i = tid + k * 1024;
        u32 x = (u32)i;
        bool r = (compL[i] == (u32)i);
        isroot[k] = r;
        u64 g = 0;
        if (r) {
            g = best[i];
            u32 lo = (u32)(g >> 12) & 0xFFFu;
            u32 hi = (u32)g & 0xFFFu;
            u32 cl = compL[lo], ch = compL[hi];
            x = (cl == (u32)i) ? ch : cl;
        }
        bkey[k] = g;
        nxtA[i] = x;
    }
    __syncthreads();

    #pragma unroll
    for (int k = 0; k < 4; ++k) {
        int i = tid + k * 1024;
        u32 nn = (u32)i;
        if (isroot[k]) {
            u32 o = nxtA[i];
            bool mutual = (nxtA[o] == (u32)i);
            nn = (mutual && ((u32)i < o)) ? (u32)i : o;
            if (nn != (u32)i)
                ws->edges[m][i] = (u32)(bkey[k] & 0xFFFFFFu);
        }
        nxtB[i] = nn;
    }
    __syncthreads();

    for (int s = 0; s < 12; ++s) {
        #pragma unroll
        for (int k = 0; k < 4; ++k) {
            int i = tid + k * 1024;
            nxtB[i] = nxtB[nxtB[i]];
        }
        __syncthreads();
    }

    u32 cnt = 0;
    #pragma unroll
    for (int k = 0; k < 4; ++k) {
        int i = tid + k * 1024;
        if (isroot[k] && nxtB[i] == (u32)i) cnt++;
    }
    #pragma unroll
    for (int off = 32; off >= 1; off >>= 1) cnt += (u32)__shfl_down((int)cnt, off, 64);
    const int lane = tid & 63, wave = tid >> 6;
    if (lane == 0) red[wave] = cnt;
    __syncthreads();

    #pragma unroll
    for (int k = 0; k < 4; ++k) {
        int i = tid + k * 1024;
        gcomp[i] = nxtB[compL[i]];
        if (isroot[k]) best[i] = INFK;
    }
    if (tid == 0) {
        u32 t = 0;
        #pragma unroll
        for (int w = 0; w < 16; ++w) t += red[w];
        ws->ncomp[m] = t;
    }
}

__launch_bounds__(256, 1)
__global__ void epi_k(const float* __restrict__ d1, const float* __restrict__ d2,
                      Ws* __restrict__ ws, float* __restrict__ out) {
    const int m = blockIdx.x, tid = threadIdx.x;
    float acc = 0.f;
    for (int i = tid; i < N; i += 256) {
        u32 pk = ws->edges[m][i];
        u32 lo = (pk >> 12) & 0xFFFu, hi = pk & 0xFFFu;
        size_t off = (size_t)lo * N + hi;
        float df = d1[off] - d2[off];     // diagonal sentinel -> 0
        acc += df * df;
    }
    #pragma unroll
    for (int off = 32; off >= 1; off >>= 1) acc += __shfl_down(acc, off, 64);
    __shared__ float part[4];
    const int lane = tid & 63, wave = tid >> 6;
    if (lane == 0) part[wave] = acc;
    __syncthreads();
    if (tid == 0) atomicAdd(out, part[0] + part[1] + part[2] + part[3]);
}

extern "C" void kernel_launch(void* const* d_in, const int* in_sizes, int n_in,
                              void* d_out, int out_size, void* d_ws, size_t ws_size,
                              hipStream_t stream) {
    (void)in_sizes; (void)n_in; (void)out_size;
    const float* d1 = (const float*)d_in[0];
    const float* d2 = (const float*)d_in[1];
    float* out = (float*)d_out;
    Ws* ws = (Ws*)d_ws;
    const bool big = (ws_size >= sizeof(Ws));   // ~4.4 MB needed for bound table

    hipMemsetAsync(d_out, 0, sizeof(float), stream);
    init_k<<<dim3(16), dim3(256), 0, stream>>>(ws);
    for (int r = 0; r < NROUNDS; ++r) {
        if (big) {
            if (r == 0) scanA_k<<<dim3(2048), dim3(256), 0, stream>>>(d1, d2, ws);
            else        scan2_k<<<dim3(2048), dim3(256), 0, stream>>>(d1, d2, ws);
        } else {
            scanF_k<<<dim3(2048), dim3(256), 0, stream>>>(d1, d2, ws, r == 0 ? 1 : 0);
        }
        hook_k<<<dim3(2), dim3(1024), 0, stream>>>(ws);
    }
    epi_k<<<dim3(2), dim3(256), 0, stream>>>(d1, d2, ws, out);
}